// Round 1
// baseline (736.573 us; speedup 1.0000x reference)
//
#include <hip/hip_runtime.h>
#include <math.h>

typedef unsigned short u16;
typedef __attribute__((ext_vector_type(8))) short short8;
typedef __attribute__((ext_vector_type(8))) unsigned short ushort8;
typedef __attribute__((ext_vector_type(4))) float floatx4;

#define NTOK 4096
#define DDIM 1024
#define FDIM 4096
#define NEXP 8
#define ROWS_PAD 10240   // 8192 + 8*256 worst-case per-expert 256-padding
#define MT256 40         // ROWS_PAD / 256

// ---------- bf16 <-> f32 (raw bits, RNE) ----------
__device__ __forceinline__ float b2f(u16 u) {
    union { unsigned u32; float f; } v; v.u32 = ((unsigned)u) << 16; return v.f;
}
__device__ __forceinline__ u16 f2b(float f) {
    union { float f; unsigned u; } v; v.f = f;
    unsigned u = v.u;
    return (u16)((u + 0x7fffu + ((u >> 16) & 1u)) >> 16);
}
__device__ __forceinline__ float bf16r(float f) { return b2f(f2b(f)); }

// async global->LDS, 16B per lane. LDS dest must be wave-uniform base + lane*16.
__device__ __forceinline__ void async16(const u16* g, u16* l) {
    __builtin_amdgcn_global_load_lds((const __attribute__((address_space(1))) void*)g,
                                     (__attribute__((address_space(3))) void*)l,
                                     16, 0, 0);
}

// counted vmcnt wait + raw barrier (no vmcnt(0) drain — the whole point)
template<int V> __device__ __forceinline__ void waitbar() {
    if constexpr (V == 8)      asm volatile("s_waitcnt vmcnt(8)\ns_barrier" ::: "memory");
    else if constexpr (V == 6) asm volatile("s_waitcnt vmcnt(6)\ns_barrier" ::: "memory");
    else if constexpr (V == 4) asm volatile("s_waitcnt vmcnt(4)\ns_barrier" ::: "memory");
    else if constexpr (V == 3) asm volatile("s_waitcnt vmcnt(3)\ns_barrier" ::: "memory");
    else                       asm volatile("s_waitcnt vmcnt(0)\ns_barrier" ::: "memory");
}

// ---------------- init + dtype probe ------------------------------------------
__global__ __launch_bounds__(256) void init_probe_kernel(const u16* __restrict__ wr,
        int* __restrict__ flag, int* __restrict__ row_token,
        float* __restrict__ row_weight, int* __restrict__ counts16) {
    int i = blockIdx.x * 256 + threadIdx.x;
    if (i < ROWS_PAD) { row_token[i] = 0; row_weight[i] = 0.f; }
    if (i < 16) counts16[i] = 0;   // counts[8] + cursor[8]
    if (blockIdx.x == 0) {
        __shared__ int cnt;
        if (threadIdx.x == 0) cnt = 0;
        __syncthreads();
        int c = 0;
        for (int k = threadIdx.x; k < 8192; k += 256) {
            int e = (wr[k] >> 7) & 0xFF;
            c += (e >= 90 && e <= 130) ? 1 : 0;
        }
        atomicAdd(&cnt, c);
        __syncthreads();
        if (threadIdx.x == 0) *flag = (cnt >= 7400) ? 1 : 0;   // 1 = bf16
    }
}

// ---------------- normalize x to bf16 ----------------------------------------
__global__ __launch_bounds__(256) void normx_kernel(const void* __restrict__ xr,
        u16* __restrict__ xb, const int* __restrict__ flag) {
    size_t i = ((size_t)blockIdx.x * 256 + threadIdx.x) * 8;
    if (*flag) {
        *(ushort8*)(xb + i) = *(const ushort8*)((const u16*)xr + i);
    } else {
        const float* xf = (const float*)xr + i;
        floatx4 a = *(const floatx4*)xf;
        floatx4 b = *(const floatx4*)(xf + 4);
        ushort8 o;
#pragma unroll
        for (int l = 0; l < 4; ++l) { o[l] = f2b(a[l]); o[4 + l] = f2b(b[l]); }
        *(ushort8*)(xb + i) = o;
    }
}

// ---------------- router: logits, top-2, softmax ------------------------------
__global__ __launch_bounds__(64) void router_kernel(const void* __restrict__ xr,
        const void* __restrict__ wrr, const int* __restrict__ flag,
        int* __restrict__ tok_e, float* __restrict__ tok_w, int* __restrict__ counts) {
    int t = blockIdx.x;
    int lane = threadIdx.x;
    int isbf = *flag;
    float acc[NEXP];
#pragma unroll
    for (int e = 0; e < NEXP; ++e) acc[e] = 0.f;
    if (isbf) {
        const u16* xrow = (const u16*)xr + (size_t)t * DDIM;
        const u16* wr = (const u16*)wrr;
        for (int j = 0; j < DDIM / 64; ++j) {
            int d = lane + j * 64;
            float xv = b2f(xrow[d]);
            ushort8 wv = *(const ushort8*)(wr + (size_t)d * NEXP);
#pragma unroll
            for (int e = 0; e < NEXP; ++e) acc[e] += xv * b2f(wv[e]);
        }
    } else {
        const float* xrow = (const float*)xr + (size_t)t * DDIM;
        const float* wr = (const float*)wrr;
        for (int j = 0; j < DDIM / 64; ++j) {
            int d = lane + j * 64;
            float xv = xrow[d];
            floatx4 w0 = *(const floatx4*)(wr + (size_t)d * NEXP);
            floatx4 w1 = *(const floatx4*)(wr + (size_t)d * NEXP + 4);
#pragma unroll
            for (int l = 0; l < 4; ++l) { acc[l] += xv * w0[l]; acc[4 + l] += xv * w1[l]; }
        }
    }
#pragma unroll
    for (int off = 32; off > 0; off >>= 1)
#pragma unroll
        for (int e = 0; e < NEXP; ++e) acc[e] += __shfl_xor(acc[e], off, 64);
    if (lane == 0) {
        float v[NEXP];
#pragma unroll
        for (int e = 0; e < NEXP; ++e) v[e] = isbf ? bf16r(acc[e]) : acc[e];
        int e0 = 0;
        for (int e = 1; e < NEXP; ++e) if (v[e] > v[e0]) e0 = e;   // lowest idx wins ties
        int e1 = (e0 == 0) ? 1 : 0;
        for (int e = 0; e < NEXP; ++e) if (e != e0 && v[e] > v[e1]) e1 = e;
        float dlt = expf(v[e1] - v[e0]);           // <= 1
        float w0 = 1.f / (1.f + dlt);
        float w1 = dlt / (1.f + dlt);
        tok_e[2 * t] = e0; tok_e[2 * t + 1] = e1;
        tok_w[2 * t]     = isbf ? bf16r(w0) : w0;
        tok_w[2 * t + 1] = isbf ? bf16r(w1) : w1;
        atomicAdd(&counts[e0], 1);
        atomicAdd(&counts[e1], 1);
    }
}

// ---------------- per-expert offsets, 256-aligned segments --------------------
__global__ void offsets_kernel(const int* counts, int* offs) {
    if (threadIdx.x == 0) {
        int o = 0; offs[0] = 0;
        for (int e = 0; e < NEXP; ++e) { o += ((counts[e] + 255) & ~255); offs[e + 1] = o; }
    }
}

// ---------------- scatter tokens into expert-sorted row list ------------------
__global__ __launch_bounds__(256) void scatter_kernel(const int* __restrict__ tok_e,
        const float* __restrict__ tok_w, const int* __restrict__ offs, int* cursor,
        int* __restrict__ row_token, float* __restrict__ row_weight,
        int* __restrict__ tok_rows) {
    int t = blockIdx.x * 256 + threadIdx.x;
    if (t >= NTOK) return;
#pragma unroll
    for (int k = 0; k < 2; ++k) {
        int e = tok_e[2 * t + k];
        int pos = offs[e] + atomicAdd(&cursor[e], 1);
        row_token[pos] = t;
        row_weight[pos] = tok_w[2 * t + k];
        tok_rows[2 * t + k] = pos;
    }
}

// ---------------- 64x64 tile transpose, dtype-aware src, bf16 dst -------------
__global__ __launch_bounds__(256) void transpose_kernel(const void* __restrict__ src,
        u16* __restrict__ dst, int R, int C, const int* __restrict__ flag) {
    __shared__ u16 tile[64][66];
    int isbf = *flag;
    size_t eoff = (size_t)blockIdx.z * R * C;
    int bc = blockIdx.x * 64;
    int br = blockIdx.y * 64;
    int tid = threadIdx.x;
#pragma unroll
    for (int c = tid; c < 512; c += 256) {
        int r = c >> 3, cc = (c & 7) * 8;
        if (isbf) {
            ushort8 v = *(const ushort8*)((const u16*)src + eoff + (size_t)(br + r) * C + bc + cc);
#pragma unroll
            for (int l = 0; l < 8; ++l) tile[r][cc + l] = v[l];
        } else {
            const float* s = (const float*)src + eoff + (size_t)(br + r) * C + bc + cc;
            floatx4 a = *(const floatx4*)s;
            floatx4 b = *(const floatx4*)(s + 4);
#pragma unroll
            for (int l = 0; l < 4; ++l) { tile[r][cc + l] = f2b(a[l]); tile[r][cc + 4 + l] = f2b(b[l]); }
        }
    }
    __syncthreads();
#pragma unroll
    for (int c = tid; c < 512; c += 256) {
        int i = c >> 3, jj = (c & 7) * 8;
        ushort8 o;
#pragma unroll
        for (int l = 0; l < 8; ++l) o[l] = tile[jj + l][i];
        *(ushort8*)(dst + eoff + (size_t)(bc + i) * R + br + jj) = o;
    }
}

// ---------------- deep-pipelined GEMM: C[256 x BN] tiles ----------------------
// 8 waves (2M x 4N), BK=32, 4-slot LDS ring, stage tile t+3 while computing t.
// Counted vmcnt (steady 2 tiles = 2*(2+LB) loads in flight), raw s_barrier only
// at tile start. K-granule XOR swizzle on LDS rows (conflict-free ds_read_b128);
// applied by pre-swizzling the GLOBAL source column so global_load_lds keeps a
// linear destination (m173/m201 pattern). Accumulation order over K identical
// to the previous kernel -> bit-identical results.
template<int BN, int K, int N, bool GATHER, bool GELU_OUT>
__global__ __launch_bounds__(512, 2) void gemm_pipe(
        const u16* __restrict__ A, const u16* __restrict__ Bw, u16* __restrict__ C,
        const int* __restrict__ row_token, const int* __restrict__ offs) {
    constexpr int NT = K / 32;            // K-tiles
    constexpr int NB = BN / 64;           // col frags per wave
    constexpr int LB = BN / 128;          // B staging loads per tile (1 or 2)
    constexpr int SLOT = 8192 + BN * 32;  // u16 per ring slot (A 16KB + B BN*64B)
    __shared__ u16 sm[4 * SLOT];

    const int tid = threadIdx.x;
    const int m0 = blockIdx.y * 256;
    const int n0 = blockIdx.x * BN;
    if (m0 >= offs[NEXP]) return;
    int e = 0;
#pragma unroll
    for (int i = 1; i <= NEXP; ++i) e += (m0 >= offs[i]) ? 1 : 0;
    if (e > 7) e = 7;
    const u16* Bb = Bw + (size_t)e * N * K;

    // staging source pointers: thread t covers tile row (a*128 + t/4),
    // source col pre-swizzled: ((t&3) ^ ((r>>1)&3)) * 8   (granule XOR)
    const int rr = tid >> 2;
    const int cshift = (((tid & 3) ^ ((rr >> 1) & 3)) * 8);
    const u16 *pA0, *pA1;
    if constexpr (GATHER) {
        pA0 = A + (size_t)row_token[m0 + rr] * K + cshift;
        pA1 = A + (size_t)row_token[m0 + 128 + rr] * K + cshift;
    } else {
        pA0 = A + (size_t)(m0 + rr) * K + cshift;
        pA1 = pA0 + (size_t)128 * K;
    }
    const u16* pB0 = Bb + (size_t)(n0 + rr) * K + cshift;
    const u16* pB1 = pB0 + (size_t)128 * K;   // used only when LB==2

    // fragment read offsets (bytes), swizzled to match staged layout.
    // XOR term is invariant under +16-row frag steps ((16i>>1)&3 == 0).
    const int lane = tid & 63;
    const int w = tid >> 6;
    const int wml = (w >> 2) * 128;          // warp_m in {0,1}
    const int wnl = (w & 3) * (BN / 4);      // warp_n in {0..3}
    const int lm = lane & 15;
    const int kb = (lane >> 4) * 16;         // k byte offset within row (64B rows)
    const int rA = wml + lm;
    const int aoff = rA * 64 + (kb ^ (((rA >> 1) & 3) << 4));
    const int rB = wnl + lm;
    const int boff = rB * 64 + (kb ^ (((rB >> 1) & 3) << 4));

    floatx4 acc[8][NB];
#pragma unroll
    for (int i = 0; i < 8; ++i)
#pragma unroll
        for (int j = 0; j < NB; ++j) acc[i][j] = (floatx4){0.f, 0.f, 0.f, 0.f};

    auto stageA = [&](int t) {
        u16* d = sm + (t & 3) * SLOT;
        async16(pA0 + t * 32, d + tid * 8);
        async16(pA1 + t * 32, d + 4096 + tid * 8);
    };
    auto stageB = [&](int t) {
        u16* d = sm + (t & 3) * SLOT + 8192;
        async16(pB0 + t * 32, d + tid * 8);
        if constexpr (LB == 2) async16(pB1 + t * 32, d + 4096 + tid * 8);
    };

    stageA(0); stageB(0); stageA(1); stageB(1); stageA(2); stageB(2);

    for (int t = 0; t < NT; ++t) {
        if (t < NT - 2)       waitbar<2 * (2 + LB)>();
        else if (t == NT - 2) waitbar<2 + LB>();
        else                  waitbar<0>();
        const char* As = (const char*)(sm + (t & 3) * SLOT);
        const char* Bs = As + 16384;
        short8 bf[NB], af[4];
#pragma unroll
        for (int j = 0; j < NB; ++j) bf[j] = *(const short8*)(Bs + boff + j * 1024);
#pragma unroll
        for (int i = 0; i < 4; ++i) af[i] = *(const short8*)(As + aoff + i * 1024);
        const bool st = (t + 3 < NT);
        if (st) stageA(t + 3);
        __builtin_amdgcn_s_setprio(1);
#pragma unroll
        for (int i = 0; i < 4; ++i)
#pragma unroll
            for (int j = 0; j < NB; ++j)
                acc[i][j] = __builtin_amdgcn_mfma_f32_16x16x32_bf16(af[i], bf[j], acc[i][j], 0, 0, 0);
        __builtin_amdgcn_s_setprio(0);
#pragma unroll
        for (int i = 0; i < 4; ++i) af[i] = *(const short8*)(As + aoff + (4 + i) * 1024);
        if (st) stageB(t + 3);
        __builtin_amdgcn_s_setprio(1);
#pragma unroll
        for (int i = 0; i < 4; ++i)
#pragma unroll
            for (int j = 0; j < NB; ++j)
                acc[4 + i][j] = __builtin_amdgcn_mfma_f32_16x16x32_bf16(af[i], bf[j], acc[4 + i][j], 0, 0, 0);
        __builtin_amdgcn_s_setprio(0);
    }

    const int rq = (lane >> 4) * 4;
#pragma unroll
    for (int i = 0; i < 8; ++i)
#pragma unroll
        for (int j = 0; j < NB; ++j)
#pragma unroll
            for (int r = 0; r < 4; ++r) {
                int row = m0 + wml + i * 16 + rq + r;
                int col = n0 + wnl + j * 16 + lm;
                float v;
                if constexpr (GELU_OUT) {
                    float hb = bf16r(acc[i][j][r]);   // ref rounds matmul to bf16 first
                    v = 0.5f * hb * (1.f + erff(hb * 0.70710678118654752f));
                } else {
                    v = acc[i][j][r];
                }
                C[(size_t)row * N + col] = f2b(v);
            }
}

// ---------------- combine: out[t] = w0*Y[r0] + w1*Y[r1] (fp32 sum) ------------
__global__ __launch_bounds__(256) void combine_kernel(const u16* __restrict__ Y,
        const int* __restrict__ tok_rows, const float* __restrict__ row_weight,
        const int* __restrict__ flag, void* __restrict__ out) {
    int c = blockIdx.x * 256 + threadIdx.x;
    int t = c >> 7;             // D/8 = 128 chunks per token
    int d0 = (c & 127) * 8;
    int r0 = tok_rows[2 * t], r1 = tok_rows[2 * t + 1];
    float w0 = row_weight[r0], w1 = row_weight[r1];
    ushort8 y0 = *(const ushort8*)(Y + (size_t)r0 * DDIM + d0);
    ushort8 y1 = *(const ushort8*)(Y + (size_t)r1 * DDIM + d0);
    float o[8];
#pragma unroll
    for (int l = 0; l < 8; ++l) o[l] = w0 * b2f(y0[l]) + w1 * b2f(y1[l]);
    if (*flag) {
        ushort8 ob;
#pragma unroll
        for (int l = 0; l < 8; ++l) ob[l] = f2b(o[l]);
        *(ushort8*)((u16*)out + (size_t)t * DDIM + d0) = ob;
    } else {
        floatx4 a, b;
#pragma unroll
        for (int l = 0; l < 4; ++l) { a[l] = o[l]; b[l] = o[4 + l]; }
        float* of = (float*)out + (size_t)t * DDIM + d0;
        *(floatx4*)of = a;
        *(floatx4*)(of + 4) = b;
    }
}

extern "C" void kernel_launch(void* const* d_in, const int* in_sizes, int n_in,
                              void* d_out, int out_size, void* d_ws, size_t ws_size,
                              hipStream_t stream) {
    const void* x  = d_in[0];
    const void* Wr = d_in[1];
    const void* W1 = d_in[2];
    const void* W2 = d_in[3];

    char* ws = (char*)d_ws;
    size_t off = 0;
    u16* xb = (u16*)(ws + off); off += (size_t)NTOK * DDIM * 2;            // 8.4 MB
    u16* H  = (u16*)(ws + off); off += (size_t)ROWS_PAD * FDIM * 2;        // 83.9 MB
    u16* WT = (u16*)(ws + off); off += (size_t)NEXP * DDIM * FDIM * 2;     // 67 MB (W1t then W2t)
    u16* Y  = (u16*)(ws + off); off += (size_t)ROWS_PAD * DDIM * 2;        // 21 MB
    int*   row_token  = (int*)(ws + off); off += ROWS_PAD * 4;
    float* row_weight = (float*)(ws + off); off += ROWS_PAD * 4;
    int*   tok_e    = (int*)(ws + off); off += NTOK * 2 * 4;
    float* tok_w    = (float*)(ws + off); off += NTOK * 2 * 4;
    int*   tok_rows = (int*)(ws + off); off += NTOK * 2 * 4;
    int*   counts16 = (int*)(ws + off); off += 16 * 4;   // counts[8] + cursor[8]
    int*   offs     = (int*)(ws + off); off += 16 * 4;
    int*   flag     = (int*)(ws + off); off += 4;
    (void)in_sizes; (void)n_in; (void)out_size; (void)ws_size;

    hipLaunchKernelGGL(init_probe_kernel, dim3(ROWS_PAD / 256), dim3(256), 0, stream,
                       (const u16*)Wr, flag, row_token, row_weight, counts16);
    hipLaunchKernelGGL(normx_kernel, dim3(NTOK * DDIM / 8 / 256), dim3(256), 0, stream,
                       x, xb, flag);
    hipLaunchKernelGGL(router_kernel, dim3(NTOK), dim3(64), 0, stream,
                       x, Wr, flag, tok_e, tok_w, counts16);
    hipLaunchKernelGGL(offsets_kernel, dim3(1), dim3(64), 0, stream, counts16, offs);
    hipLaunchKernelGGL(scatter_kernel, dim3(16), dim3(256), 0, stream,
                       tok_e, tok_w, offs, counts16 + 8, row_token, row_weight, tok_rows);
    hipLaunchKernelGGL(transpose_kernel, dim3(FDIM / 64, DDIM / 64, NEXP), dim3(256), 0, stream,
                       W1, WT, DDIM, FDIM, flag);   // [D][F] -> [F][D]
    hipLaunchKernelGGL((gemm_pipe<256, DDIM, FDIM, true, true>), dim3(FDIM / 256, MT256),
                       dim3(512), 0, stream, xb, WT, H, row_token, offs);
    hipLaunchKernelGGL(transpose_kernel, dim3(DDIM / 64, FDIM / 64, NEXP), dim3(256), 0, stream,
                       W2, WT, FDIM, DDIM, flag);   // [F][D] -> [D][F], reuses W1t region
    hipLaunchKernelGGL((gemm_pipe<128, FDIM, DDIM, false, false>), dim3(DDIM / 128, MT256),
                       dim3(512), 0, stream, H, WT, Y, row_token, offs);
    hipLaunchKernelGGL(combine_kernel, dim3(NTOK * DDIM / 8 / 256), dim3(256), 0, stream,
                       Y, tok_rows, row_weight, flag, d_out);
}

// Round 2
// 714.287 us; speedup vs baseline: 1.0312x; 1.0312x over previous
//
#include <hip/hip_runtime.h>
#include <math.h>

typedef unsigned short u16;
typedef __attribute__((ext_vector_type(8))) short short8;
typedef __attribute__((ext_vector_type(8))) unsigned short ushort8;
typedef __attribute__((ext_vector_type(4))) float floatx4;

#define NTOK 4096
#define DDIM 1024
#define FDIM 4096
#define NEXP 8
#define ROWS_PAD 9216   // 8192 + worst-case per-expert 128-padding
#define MTILES 72       // ROWS_PAD / 128

// ---------- bf16 <-> f32 (raw bits, RNE) ----------
__device__ __forceinline__ float b2f(u16 u) {
    union { unsigned u32; float f; } v; v.u32 = ((unsigned)u) << 16; return v.f;
}
__device__ __forceinline__ u16 f2b(float f) {
    union { float f; unsigned u; } v; v.f = f;
    unsigned u = v.u;
    return (u16)((u + 0x7fffu + ((u >> 16) & 1u)) >> 16);
}
__device__ __forceinline__ float bf16r(float f) { return b2f(f2b(f)); }

// async global->LDS, 16B per lane. LDS dest must be wave-uniform base + lane*16.
__device__ __forceinline__ void async16(const u16* g, u16* l) {
    __builtin_amdgcn_global_load_lds((const __attribute__((address_space(1))) void*)g,
                                     (__attribute__((address_space(3))) void*)l,
                                     16, 0, 0);
}

// counted vmcnt wait + raw barrier (never drain to 0 in steady state)
template<int V> __device__ __forceinline__ void waitbar() {
    if constexpr (V == 6)      asm volatile("s_waitcnt vmcnt(6)\ns_barrier" ::: "memory");
    else                       asm volatile("s_waitcnt vmcnt(0)\ns_barrier" ::: "memory");
}

// ---------------- init + dtype probe ------------------------------------------
__global__ __launch_bounds__(256) void init_probe_kernel(const u16* __restrict__ wr,
        int* __restrict__ flag, int* __restrict__ row_token,
        float* __restrict__ row_weight, int* __restrict__ counts16) {
    int i = blockIdx.x * 256 + threadIdx.x;
    if (i < ROWS_PAD) { row_token[i] = 0; row_weight[i] = 0.f; }
    if (i < 16) counts16[i] = 0;   // counts[8] + cursor[8]
    if (blockIdx.x == 0) {
        __shared__ int cnt;
        if (threadIdx.x == 0) cnt = 0;
        __syncthreads();
        int c = 0;
        for (int k = threadIdx.x; k < 8192; k += 256) {
            int e = (wr[k] >> 7) & 0xFF;
            c += (e >= 90 && e <= 130) ? 1 : 0;
        }
        atomicAdd(&cnt, c);
        __syncthreads();
        if (threadIdx.x == 0) *flag = (cnt >= 7400) ? 1 : 0;   // 1 = bf16
    }
}

// ---------------- normalize x to bf16 ----------------------------------------
__global__ __launch_bounds__(256) void normx_kernel(const void* __restrict__ xr,
        u16* __restrict__ xb, const int* __restrict__ flag) {
    size_t i = ((size_t)blockIdx.x * 256 + threadIdx.x) * 8;
    if (*flag) {
        *(ushort8*)(xb + i) = *(const ushort8*)((const u16*)xr + i);
    } else {
        const float* xf = (const float*)xr + i;
        floatx4 a = *(const floatx4*)xf;
        floatx4 b = *(const floatx4*)(xf + 4);
        ushort8 o;
#pragma unroll
        for (int l = 0; l < 4; ++l) { o[l] = f2b(a[l]); o[4 + l] = f2b(b[l]); }
        *(ushort8*)(xb + i) = o;
    }
}

// ---------------- router: logits, top-2, softmax ------------------------------
__global__ __launch_bounds__(64) void router_kernel(const void* __restrict__ xr,
        const void* __restrict__ wrr, const int* __restrict__ flag,
        int* __restrict__ tok_e, float* __restrict__ tok_w, int* __restrict__ counts) {
    int t = blockIdx.x;
    int lane = threadIdx.x;
    int isbf = *flag;
    float acc[NEXP];
#pragma unroll
    for (int e = 0; e < NEXP; ++e) acc[e] = 0.f;
    if (isbf) {
        const u16* xrow = (const u16*)xr + (size_t)t * DDIM;
        const u16* wr = (const u16*)wrr;
        for (int j = 0; j < DDIM / 64; ++j) {
            int d = lane + j * 64;
            float xv = b2f(xrow[d]);
            ushort8 wv = *(const ushort8*)(wr + (size_t)d * NEXP);
#pragma unroll
            for (int e = 0; e < NEXP; ++e) acc[e] += xv * b2f(wv[e]);
        }
    } else {
        const float* xrow = (const float*)xr + (size_t)t * DDIM;
        const float* wr = (const float*)wrr;
        for (int j = 0; j < DDIM / 64; ++j) {
            int d = lane + j * 64;
            float xv = xrow[d];
            floatx4 w0 = *(const floatx4*)(wr + (size_t)d * NEXP);
            floatx4 w1 = *(const floatx4*)(wr + (size_t)d * NEXP + 4);
#pragma unroll
            for (int l = 0; l < 4; ++l) { acc[l] += xv * w0[l]; acc[4 + l] += xv * w1[l]; }
        }
    }
#pragma unroll
    for (int off = 32; off > 0; off >>= 1)
#pragma unroll
        for (int e = 0; e < NEXP; ++e) acc[e] += __shfl_xor(acc[e], off, 64);
    if (lane == 0) {
        float v[NEXP];
#pragma unroll
        for (int e = 0; e < NEXP; ++e) v[e] = isbf ? bf16r(acc[e]) : acc[e];
        int e0 = 0;
        for (int e = 1; e < NEXP; ++e) if (v[e] > v[e0]) e0 = e;   // lowest idx wins ties
        int e1 = (e0 == 0) ? 1 : 0;
        for (int e = 0; e < NEXP; ++e) if (e != e0 && v[e] > v[e1]) e1 = e;
        float dlt = expf(v[e1] - v[e0]);           // <= 1
        float w0 = 1.f / (1.f + dlt);
        float w1 = dlt / (1.f + dlt);
        tok_e[2 * t] = e0; tok_e[2 * t + 1] = e1;
        tok_w[2 * t]     = isbf ? bf16r(w0) : w0;
        tok_w[2 * t + 1] = isbf ? bf16r(w1) : w1;
        atomicAdd(&counts[e0], 1);
        atomicAdd(&counts[e1], 1);
    }
}

// ---------------- per-expert offsets, 128-aligned segments --------------------
__global__ void offsets_kernel(const int* counts, int* offs) {
    if (threadIdx.x == 0) {
        int o = 0; offs[0] = 0;
        for (int e = 0; e < NEXP; ++e) { o += ((counts[e] + 127) & ~127); offs[e + 1] = o; }
    }
}

// ---------------- scatter tokens into expert-sorted row list ------------------
__global__ __launch_bounds__(256) void scatter_kernel(const int* __restrict__ tok_e,
        const float* __restrict__ tok_w, const int* __restrict__ offs, int* cursor,
        int* __restrict__ row_token, float* __restrict__ row_weight,
        int* __restrict__ tok_rows) {
    int t = blockIdx.x * 256 + threadIdx.x;
    if (t >= NTOK) return;
#pragma unroll
    for (int k = 0; k < 2; ++k) {
        int e = tok_e[2 * t + k];
        int pos = offs[e] + atomicAdd(&cursor[e], 1);
        row_token[pos] = t;
        row_weight[pos] = tok_w[2 * t + k];
        tok_rows[2 * t + k] = pos;
    }
}

// ---------------- 64x64 tile transpose, dtype-aware src, bf16 dst -------------
__global__ __launch_bounds__(256) void transpose_kernel(const void* __restrict__ src,
        u16* __restrict__ dst, int R, int C, const int* __restrict__ flag) {
    __shared__ u16 tile[64][66];
    int isbf = *flag;
    size_t eoff = (size_t)blockIdx.z * R * C;
    int bc = blockIdx.x * 64;
    int br = blockIdx.y * 64;
    int tid = threadIdx.x;
#pragma unroll
    for (int c = tid; c < 512; c += 256) {
        int r = c >> 3, cc = (c & 7) * 8;
        if (isbf) {
            ushort8 v = *(const ushort8*)((const u16*)src + eoff + (size_t)(br + r) * C + bc + cc);
#pragma unroll
            for (int l = 0; l < 8; ++l) tile[r][cc + l] = v[l];
        } else {
            const float* s = (const float*)src + eoff + (size_t)(br + r) * C + bc + cc;
            floatx4 a = *(const floatx4*)s;
            floatx4 b = *(const floatx4*)(s + 4);
#pragma unroll
            for (int l = 0; l < 4; ++l) { tile[r][cc + l] = f2b(a[l]); tile[r][cc + 4 + l] = f2b(b[l]); }
        }
    }
    __syncthreads();
#pragma unroll
    for (int c = tid; c < 512; c += 256) {
        int i = c >> 3, jj = (c & 7) * 8;
        ushort8 o;
#pragma unroll
        for (int l = 0; l < 8; ++l) o[l] = tile[jj + l][i];
        *(ushort8*)(dst + eoff + (size_t)(bc + i) * R + br + jj) = o;
    }
}

// ---------------- ring-pipelined GEMM body ------------------------------------
// BM=128, BN=256, BK=32. 256 threads = 4 waves (2m x 2n), wave tile 64x128
// (ds_read:MFMA = 12:32). 3-slot LDS ring (72 KB -> 2 blocks/CU for TLP),
// stage t+2 while computing t, steady s_waitcnt vmcnt(6) (one slot = 6 loads).
// K-granule XOR swizzle via pre-swizzled GLOBAL source (linear LDS dest),
// conflict-free ds_read_b128 (verified: 0 conflicts in round 1).
// n-outer linearization + XCD chunk swizzle keeps one 512KB B-panel per XCD L2.
template<int K, int N, bool GATHER, bool GELU_OUT>
__device__ __forceinline__ void gemm_body(const u16* __restrict__ A,
        const u16* __restrict__ Bw, u16* __restrict__ C,
        const int* __restrict__ row_token, const int* __restrict__ offs) {
    constexpr int NT = K / 32;
    __shared__ u16 sm[3 * 12288];    // 3 slots x (A 8KB + B 16KB) = 72 KB

    const int tid = threadIdx.x;
    const int nwg = gridDim.x;                     // multiple of 8
    int b = blockIdx.x;
    b = (b & 7) * (nwg >> 3) + (b >> 3);           // XCD chunk swizzle (bijective)
    const int m_idx = b % MTILES;                  // n-outer: consecutive b share n-panel
    const int n_idx = b / MTILES;
    const int m0 = m_idx * 128;
    const int n0 = n_idx * 256;
    if (m0 >= offs[NEXP]) return;
    int e = 0;
#pragma unroll
    for (int i = 1; i <= NEXP; ++i) e += (m0 >= offs[i]) ? 1 : 0;
    if (e > 7) e = 7;
    const u16* Bb = Bw + (size_t)e * (size_t)N * K;

    // staging: thread t covers tile row (chunk*64 + t/4), granule t&3,
    // source col pre-swizzled by ((t&3) ^ ((row>>1)&3))*8; chunk offsets are
    // multiples of 64 (== 0 mod 8) so the XOR term is chunk-invariant.
    const int rr = tid >> 2;
    const int cshift = ((tid & 3) ^ ((rr >> 1) & 3)) * 8;
    const u16 *pA0, *pA1;
    if constexpr (GATHER) {
        pA0 = A + (size_t)row_token[m0 + rr] * K + cshift;
        pA1 = A + (size_t)row_token[m0 + 64 + rr] * K + cshift;
    } else {
        pA0 = A + (size_t)(m0 + rr) * K + cshift;
        pA1 = pA0 + (size_t)64 * K;
    }
    const u16* pB0 = Bb + (size_t)(n0 + rr) * K + cshift;
    const u16* pB1 = pB0 + (size_t)64 * K;
    const u16* pB2 = pB0 + (size_t)128 * K;
    const u16* pB3 = pB0 + (size_t)192 * K;

    // fragment read offsets (bytes), XOR matches staged layout; the XOR term is
    // invariant under +16-row frag steps.
    const int lane = tid & 63;
    const int w = tid >> 6;
    const int wm = (w >> 1) * 64;
    const int wn = (w & 1) * 128;
    const int lm = lane & 15;
    const int kb = (lane >> 4) * 16;
    const int rA = wm + lm;
    const int aoff = rA * 64 + (kb ^ (((rA >> 1) & 3) << 4));
    const int rB = wn + lm;
    const int boff = 8192 + rB * 64 + (kb ^ (((rB >> 1) & 3) << 4));

    floatx4 acc[4][8];
#pragma unroll
    for (int i = 0; i < 4; ++i)
#pragma unroll
        for (int j = 0; j < 8; ++j) acc[i][j] = (floatx4){0.f, 0.f, 0.f, 0.f};

    auto stage = [&](int t, int slot) {
        u16* d = sm + slot * 12288;
        const int ko = t * 32;
        async16(pA0 + ko, d + tid * 8);
        async16(pA1 + ko, d + 2048 + tid * 8);
        async16(pB0 + ko, d + 4096 + tid * 8);
        async16(pB1 + ko, d + 6144 + tid * 8);
        async16(pB2 + ko, d + 8192 + tid * 8);
        async16(pB3 + ko, d + 10240 + tid * 8);
    };

    stage(0, 0);
    stage(1, 1);

    int rs = 0;   // slot holding tile t
    for (int t = 0; t < NT; ++t) {
        if (t < NT - 1) waitbar<6>(); else waitbar<0>();
        const char* Ls = (const char*)sm + rs * 24576;
        short8 bf[8], af[4];
#pragma unroll
        for (int j = 0; j < 8; ++j) bf[j] = *(const short8*)(Ls + boff + j * 1024);
#pragma unroll
        for (int i = 0; i < 4; ++i) af[i] = *(const short8*)(Ls + aoff + i * 1024);
        if (t + 2 < NT) stage(t + 2, rs == 0 ? 2 : rs - 1);   // slot (t+2)%3
        __builtin_amdgcn_s_setprio(1);
#pragma unroll
        for (int i = 0; i < 4; ++i)
#pragma unroll
            for (int j = 0; j < 8; ++j)
                acc[i][j] = __builtin_amdgcn_mfma_f32_16x16x32_bf16(af[i], bf[j], acc[i][j], 0, 0, 0);
        __builtin_amdgcn_s_setprio(0);
        rs = (rs == 2) ? 0 : rs + 1;
    }

    const int rq = (lane >> 4) * 4;
#pragma unroll
    for (int i = 0; i < 4; ++i)
#pragma unroll
        for (int j = 0; j < 8; ++j)
#pragma unroll
            for (int r = 0; r < 4; ++r) {
                int row = m0 + wm + i * 16 + rq + r;
                int col = n0 + wn + j * 16 + lm;
                float v;
                if constexpr (GELU_OUT) {
                    float hb = bf16r(acc[i][j][r]);   // ref rounds matmul to bf16 first
                    v = 0.5f * hb * (1.f + erff(hb * 0.70710678118654752f));
                } else {
                    v = acc[i][j][r];
                }
                C[(size_t)row * N + col] = f2b(v);
            }
}

__global__ __launch_bounds__(256, 2) void gemm1_ring(const u16* __restrict__ A,
        const u16* __restrict__ Bw, u16* __restrict__ C,
        const int* __restrict__ row_token, const int* __restrict__ offs) {
    gemm_body<DDIM, FDIM, true, true>(A, Bw, C, row_token, offs);
}

__global__ __launch_bounds__(256, 2) void gemm2_ring(const u16* __restrict__ A,
        const u16* __restrict__ Bw, u16* __restrict__ C,
        const int* __restrict__ row_token, const int* __restrict__ offs) {
    gemm_body<FDIM, DDIM, false, false>(A, Bw, C, row_token, offs);
}

// ---------------- combine: out[t] = w0*Y[r0] + w1*Y[r1] (fp32 sum) ------------
__global__ __launch_bounds__(256) void combine_kernel(const u16* __restrict__ Y,
        const int* __restrict__ tok_rows, const float* __restrict__ row_weight,
        const int* __restrict__ flag, void* __restrict__ out) {
    int c = blockIdx.x * 256 + threadIdx.x;
    int t = c >> 7;             // D/8 = 128 chunks per token
    int d0 = (c & 127) * 8;
    int r0 = tok_rows[2 * t], r1 = tok_rows[2 * t + 1];
    float w0 = row_weight[r0], w1 = row_weight[r1];
    ushort8 y0 = *(const ushort8*)(Y + (size_t)r0 * DDIM + d0);
    ushort8 y1 = *(const ushort8*)(Y + (size_t)r1 * DDIM + d0);
    float o[8];
#pragma unroll
    for (int l = 0; l < 8; ++l) o[l] = w0 * b2f(y0[l]) + w1 * b2f(y1[l]);
    if (*flag) {
        ushort8 ob;
#pragma unroll
        for (int l = 0; l < 8; ++l) ob[l] = f2b(o[l]);
        *(ushort8*)((u16*)out + (size_t)t * DDIM + d0) = ob;
    } else {
        floatx4 a, b;
#pragma unroll
        for (int l = 0; l < 4; ++l) { a[l] = o[l]; b[l] = o[4 + l]; }
        float* of = (float*)out + (size_t)t * DDIM + d0;
        *(floatx4*)of = a;
        *(floatx4*)(of + 4) = b;
    }
}

extern "C" void kernel_launch(void* const* d_in, const int* in_sizes, int n_in,
                              void* d_out, int out_size, void* d_ws, size_t ws_size,
                              hipStream_t stream) {
    const void* x  = d_in[0];
    const void* Wr = d_in[1];
    const void* W1 = d_in[2];
    const void* W2 = d_in[3];

    char* ws = (char*)d_ws;
    size_t off = 0;
    u16* xb = (u16*)(ws + off); off += (size_t)NTOK * DDIM * 2;            // 8.4 MB
    u16* H  = (u16*)(ws + off); off += (size_t)ROWS_PAD * FDIM * 2;        // 75.5 MB
    u16* WT = (u16*)(ws + off); off += (size_t)NEXP * DDIM * FDIM * 2;     // 67 MB (W1t then W2t)
    u16* Y  = (u16*)(ws + off); off += (size_t)ROWS_PAD * DDIM * 2;        // 18.9 MB
    int*   row_token  = (int*)(ws + off); off += ROWS_PAD * 4;
    float* row_weight = (float*)(ws + off); off += ROWS_PAD * 4;
    int*   tok_e    = (int*)(ws + off); off += NTOK * 2 * 4;
    float* tok_w    = (float*)(ws + off); off += NTOK * 2 * 4;
    int*   tok_rows = (int*)(ws + off); off += NTOK * 2 * 4;
    int*   counts16 = (int*)(ws + off); off += 16 * 4;   // counts[8] + cursor[8]
    int*   offs     = (int*)(ws + off); off += 16 * 4;
    int*   flag     = (int*)(ws + off); off += 4;
    (void)in_sizes; (void)n_in; (void)out_size; (void)ws_size;

    hipLaunchKernelGGL(init_probe_kernel, dim3(ROWS_PAD / 256), dim3(256), 0, stream,
                       (const u16*)Wr, flag, row_token, row_weight, counts16);
    hipLaunchKernelGGL(normx_kernel, dim3(NTOK * DDIM / 8 / 256), dim3(256), 0, stream,
                       x, xb, flag);
    hipLaunchKernelGGL(router_kernel, dim3(NTOK), dim3(64), 0, stream,
                       x, Wr, flag, tok_e, tok_w, counts16);
    hipLaunchKernelGGL(offsets_kernel, dim3(1), dim3(64), 0, stream, counts16, offs);
    hipLaunchKernelGGL(scatter_kernel, dim3(16), dim3(256), 0, stream,
                       tok_e, tok_w, offs, counts16 + 8, row_token, row_weight, tok_rows);
    hipLaunchKernelGGL(transpose_kernel, dim3(FDIM / 64, DDIM / 64, NEXP), dim3(256), 0, stream,
                       W1, WT, DDIM, FDIM, flag);   // [D][F] -> [F][D]
    hipLaunchKernelGGL(gemm1_ring, dim3((FDIM / 256) * MTILES), dim3(256), 0, stream,
                       xb, WT, H, row_token, offs);
    hipLaunchKernelGGL(transpose_kernel, dim3(DDIM / 64, FDIM / 64, NEXP), dim3(256), 0, stream,
                       W2, WT, FDIM, DDIM, flag);   // [F][D] -> [D][F], reuses W1t region
    hipLaunchKernelGGL(gemm2_ring, dim3((DDIM / 256) * MTILES), dim3(256), 0, stream,
                       H, WT, Y, row_token, offs);
    hipLaunchKernelGGL(combine_kernel, dim3(NTOK * DDIM / 8 / 256), dim3(256), 0, stream,
                       Y, tok_rows, row_weight, flag, d_out);
}